// Round 16
// baseline (169.821 us; speedup 1.0000x reference)
//
#include <hip/hip_runtime.h>
#include <hip/hip_bf16.h>
#include <math.h>

constexpr int BB = 4;
constexpr int NN = 4096;
constexpr int CC = 512;
constexpr int HH = 8;
constexpr int DD = 64;
constexpr int NCNT = NN - 2;

typedef __bf16 bf16x8 __attribute__((ext_vector_type(8)));
typedef float f32x4 __attribute__((ext_vector_type(4)));

__device__ __forceinline__ float b2f(ushort u) {
  unsigned v = ((unsigned)u) << 16;
  return __builtin_bit_cast(float, v);
}
__device__ __forceinline__ ushort f2b(float f) {
  __hip_bfloat16 h = __float2bfloat16(f);
  return __builtin_bit_cast(ushort, h);
}
__device__ __forceinline__ void gload16(const ushort* g, ushort* l) {
  __builtin_amdgcn_global_load_lds(
      (const __attribute__((address_space(1))) unsigned int*)g,
      (__attribute__((address_space(3))) unsigned int*)l, 16, 0, 0);
}

// ---------------------------------------------------------------------------
// K_FRONT: fused independent prep work, branch on blockIdx.
//   [0,1024)    counts_prep: float4-vectorized second-diff counts + x -> bf16
//   [1024,1536) pe: spectral PE conv path (8 positions per block)
//   [1536,1792) prep_h: wqkv rows 0..1023 -> bf16
//   [1792,1856) prep_wvt: Wv^T -> bf16 hi/lo
// ---------------------------------------------------------------------------
__global__ __launch_bounds__(512) void k_front(
    const float* __restrict__ x, int* __restrict__ pcntP,
    int* __restrict__ pcntV, ushort* __restrict__ Xh,
    const float* __restrict__ omega,
    const float* __restrict__ w1, const float* __restrict__ b1,
    const float* __restrict__ w2, const float* __restrict__ b2,
    float* __restrict__ pe2,
    const float* __restrict__ wqkv, ushort* __restrict__ Whqk,
    ushort* __restrict__ Wvth, ushort* __restrict__ Wvtl) {
  __shared__ __attribute__((aligned(16))) char sm[16896];
  const int blk = blockIdx.x;
  const int tid = threadIdx.x;

  if (blk < 1024) {
    // ---- counts_prep, float4 along c: 4 row-groups x 128 threads ----
    int b = blk >> 8;
    int tile = blk & 255;
    int g = tid >> 7;            // row group 0..3
    int cq = tid & 127;          // c-quad index
    int c4 = cq * 4;
    int lane = tid & 63;
    int r0 = tile * 16 + g * 4;  // first owned row
    const float* xb = x + (size_t)b * NN * CC + c4;

    // 6 independent float4 loads: rows r0..r0+5 (clamped)
    float4 v[6];
    #pragma unroll
    for (int r = 0; r < 6; ++r) {
      int row = r0 + r;
      v[r] = *(const float4*)&xb[(size_t)(row < NN ? row : NN - 1) * CC];
    }

    // Xh writes for owned rows (ushort4, coalesced)
    #pragma unroll
    for (int r = 0; r < 4; ++r) {
      ushort4 h;
      ((ushort*)&h)[0] = f2b(v[r].x);
      ((ushort*)&h)[1] = f2b(v[r].y);
      ((ushort*)&h)[2] = f2b(v[r].z);
      ((ushort*)&h)[3] = f2b(v[r].w);
      *(ushort4*)&Xh[((size_t)b * NN + r0 + r) * CC + c4] = h;
    }

    // packed counts: neg (peak) low 16, pos (valley) high 16
    unsigned* red = (unsigned*)sm;  // [16]
    if (tid < 16) red[tid] = 0;
    __syncthreads();
    #pragma unroll
    for (int r = 0; r < 4; ++r) {
      int i = r0 + r;
      if (i < NCNT) {  // uniform across the 128-thread group
        float d2x = (v[r + 2].x - v[r + 1].x) - (v[r + 1].x - v[r].x);
        float d2y = (v[r + 2].y - v[r + 1].y) - (v[r + 1].y - v[r].y);
        float d2z = (v[r + 2].z - v[r + 1].z) - (v[r + 1].z - v[r].z);
        float d2w = (v[r + 2].w - v[r + 1].w) - (v[r + 1].w - v[r].w);
        unsigned neg = (d2x < 0.f) + (d2y < 0.f) + (d2z < 0.f) + (d2w < 0.f);
        unsigned pos = (d2x > 0.f) + (d2y > 0.f) + (d2z > 0.f) + (d2w > 0.f);
        unsigned packed = neg | (pos << 16);
        #pragma unroll
        for (int off = 32; off > 0; off >>= 1)
          packed += __shfl_down(packed, off);
        if (lane == 0) atomicAdd(&red[g * 4 + r], packed);
      }
    }
    __syncthreads();
    if (tid < 16) {
      int i = tile * 16 + tid;
      unsigned p = red[tid];
      pcntP[b * NN + i] = (i < NCNT) ? (int)(p & 0xffffu) : 0;
      pcntV[b * NN + i] = (i < NCNT) ? (int)(p >> 16) : 0;
    }
  } else if (blk < 1536) {
    // ---- pe: 8 positions per 512-thr block ----
    int pblk = blk - 1024;
    int g = tid >> 6;        // 0..7
    int j = tid & 63;
    int n = pblk * 8 + g;
    float (*pec)[3][64] = (float (*)[3][64])sm;            // 6144 B
    float (*hs)[128] = (float (*)[128])(sm + 6144);        // 4096 B
    for (int t = 0; t < 3; ++t) {
      int m = n + t - 1;
      float v = 0.f;
      if (m >= 0 && m < NN) {
        int l1 = m >> 6, l2 = m & 63;
        float rel = (float)(l1 - l2);
        v = (j < 32) ? sinf(rel * omega[j]) : cosf(rel * omega[j - 32]);
      }
      pec[g][t][j] = v;
    }
    __syncthreads();
    for (int o = j; o < 128; o += 64) {
      int ci = o >> 1;
      float hv = b1[o];
      #pragma unroll
      for (int t = 0; t < 3; ++t) hv += pec[g][t][ci] * w1[o * 3 + t];
      hv = 0.5f * hv * (1.f + erff(hv * 0.70710678118654752f));
      hs[g][o] = hv;
    }
    __syncthreads();
    float acc = b2[j];
    for (int o = 0; o < 128; ++o) acc += hs[g][o] * w2[j * 128 + o];
    pe2[(size_t)j * NN + n] = acc;
  } else if (blk < 1792) {
    // ---- prep_h: wqkv rows 0..1023 -> bf16 ----
    int hblk = blk - 1536;
    int idx4 = (hblk * 512 + tid) * 4;
    float4 v = *(const float4*)&wqkv[idx4];
    ushort4 h;
    ((ushort*)&h)[0] = f2b(v.x);
    ((ushort*)&h)[1] = f2b(v.y);
    ((ushort*)&h)[2] = f2b(v.z);
    ((ushort*)&h)[3] = f2b(v.w);
    *(ushort4*)&Whqk[idx4] = h;
  } else {
    // ---- prep_wvt (256 active threads) ----
    int wblk = blk - 1792;
    int bx = wblk & 7;
    int by = wblk >> 3;
    float (*t)[65] = (float (*)[65])sm;
    if (tid < 256) {
      #pragma unroll
      for (int it = 0; it < 4; ++it) {
        int idx = tid + it * 256;
        int r = idx >> 4;
        int c4 = (idx & 15) * 4;
        float4 v = *(const float4*)&wqkv[(size_t)(1024 + by * 64 + r) * 512 + bx * 64 + c4];
        t[r][c4] = v.x; t[r][c4 + 1] = v.y; t[r][c4 + 2] = v.z; t[r][c4 + 3] = v.w;
      }
    }
    __syncthreads();
    if (tid < 256) {
      #pragma unroll
      for (int it = 0; it < 4; ++it) {
        int idx = tid + it * 256;
        int r = idx >> 4;
        int c4 = (idx & 15) * 4;
        ushort4 h4, l4;
        #pragma unroll
        for (int q = 0; q < 4; ++q) {
          float v = t[c4 + q][r];
          ushort hi = f2b(v);
          ((ushort*)&h4)[q] = hi;
          ((ushort*)&l4)[q] = f2b(v - b2f(hi));
        }
        size_t o = (size_t)(bx * 64 + r) * 512 + by * 64 + c4;
        *(ushort4*)&Wvth[o] = h4;
        *(ushort4*)&Wvtl[o] = l4;
      }
    }
  }
}

// ---------------------------------------------------------------------------
// K_MID1: blk 0..15 etab2, blk 16 gatepe.
// ---------------------------------------------------------------------------
__global__ __launch_bounds__(256) void k_mid1(
    const float* __restrict__ lpw, const float* __restrict__ lvw,
    const int* __restrict__ pcntP, const int* __restrict__ pcntV,
    float* __restrict__ etabP, float* __restrict__ etabV,
    float* __restrict__ fcntP, float* __restrict__ fcntV,
    const float* __restrict__ pe2, const float* __restrict__ wg,
    const float* __restrict__ bg, float* __restrict__ gpe) {
  const int blk = blockIdx.x;
  const int tid = threadIdx.x;
  if (blk < 16) {
    int i = blk * 256 + tid;
    float ipw = expf(-lpw[0]);
    float ivw = expf(-lvw[0]);
    float t1 = (float)i * ipw;
    float t2 = (float)i * ivw;
    etabP[i] = expf(-t1 * t1);
    etabV[i] = expf(-t2 * t2);
    fcntP[i] = (float)(pcntP[i] + pcntP[NN + i] + pcntP[2 * NN + i] + pcntP[3 * NN + i]);
    fcntV[i] = (float)(pcntV[i] + pcntV[NN + i] + pcntV[2 * NN + i] + pcntV[3 * NN + i]);
  } else {
    int j = tid & 63, part = tid >> 6;
    float s = 0.f;
    const float* row = pe2 + (size_t)j * NN + part * 1024;
    for (int t = 0; t < 1024; ++t) s += row[t];
    __shared__ float ps[4][64];
    __shared__ float mean[64];
    ps[part][j] = s;
    __syncthreads();
    if (tid < 64) mean[j] = (ps[0][j] + ps[1][j] + ps[2][j] + ps[3][j]) * (1.f / 4096.f);
    __syncthreads();
    if (tid < 64) {
      float g = bg[j];
      for (int k2 = 0; k2 < 64; ++k2) g += wg[j * 64 + k2] * mean[k2];
      gpe[j] = 1.f / (1.f + expf(-g));
    }
  }
}

// ---------------------------------------------------------------------------
// K_MID2: blk 0..4095 gsum, blk 4096..5119 ropemul.
// ---------------------------------------------------------------------------
__global__ __launch_bounds__(256) void k_mid2(
    const float* __restrict__ fcntP, const float* __restrict__ fcntV,
    const float* __restrict__ etabP, const float* __restrict__ etabV,
    float* __restrict__ attn,
    const float* __restrict__ pe2, const float* __restrict__ gpe,
    float* __restrict__ ropem) {
  const int blk = blockIdx.x;
  const int tid = threadIdx.x;
  if (blk < 4096) {
    int p = blk;
    float acc = 0.f;
    for (int i = tid; i < NCNT; i += 256) {
      int a = p - 1 - i;
      a = a < 0 ? -a : a;
      acc += fcntP[i] * etabP[a] + fcntV[i] * etabV[a];
    }
    __shared__ float red[256];
    red[tid] = acc;
    __syncthreads();
    for (int s = 128; s > 0; s >>= 1) {
      if (tid < s) red[tid] += red[tid + s];
      __syncthreads();
    }
    if (tid == 0) attn[p] = red[0];
  } else {
    int idx = (blk - 4096) * 256 + tid;
    int n = idx >> 6, dd = idx & 63;
    ropem[idx] = 1.f + pe2[(size_t)dd * NN + n] * gpe[n >> 6] * 0.35355339059327373f;
  }
}

// ---------------------------------------------------------------------------
// K2b: min-max normalize
// ---------------------------------------------------------------------------
__global__ void k_norm(const float* __restrict__ attn, float* __restrict__ gate) {
  int tid = threadIdx.x;  // 1024
  float v0 = attn[tid], v1 = attn[tid + 1024], v2 = attn[tid + 2048], v3 = attn[tid + 3072];
  float mn = fminf(fminf(v0, v1), fminf(v2, v3));
  float mx = fmaxf(fmaxf(v0, v1), fmaxf(v2, v3));
  __shared__ float rmn[1024], rmx[1024];
  rmn[tid] = mn; rmx[tid] = mx;
  __syncthreads();
  for (int s = 512; s > 0; s >>= 1) {
    if (tid < s) {
      rmn[tid] = fminf(rmn[tid], rmn[tid + s]);
      rmx[tid] = fmaxf(rmx[tid], rmx[tid + s]);
    }
    __syncthreads();
  }
  float lo = rmn[0];
  float denom = rmx[0] - rmn[0] + 1e-6f;
  gate[tid]        = (v0 - lo) / denom;
  gate[tid + 1024] = (v1 - lo) / denom;
  gate[tid + 2048] = (v2 - lo) / denom;
  gate[tid + 3072] = (v3 - lo) / denom;
}

// ---------------------------------------------------------------------------
// Fat-M GEMM: 256 x BN tile, BK=32, 8 waves (4m x 2n), 512 threads, 2 LDS
// buffers, one __syncthreads per step, fully unrolled, zero-conflict swizzle.
// EPI=1: qk epilogue (gate, elu+1, rope; q/k TRANSPOSED [bh][d][n], packed).
// EPI=2: out epilogue (gate*acc + beff[b][col], f32 out, per-batch B).
// ---------------------------------------------------------------------------
template <int BN, int EPI>
__global__ __launch_bounds__(512) void k_gemm8(
    const ushort* __restrict__ Ag, const ushort* __restrict__ Bgh,
    const float* __restrict__ bias, const float* __restrict__ gate,
    const float* __restrict__ ropem,
    float* __restrict__ outF, ushort* __restrict__ qT, ushort* __restrict__ kT,
    int ntn, int ncols) {
  constexpr int NF = BN / 32;
  constexpr int BCH = BN / 16;
  const int nwg = gridDim.x;
  const int hw = blockIdx.x;
  const int logical = (hw & 7) * (nwg >> 3) + (hw >> 3);
  const int m0 = (logical / ntn) * 256, n0 = (logical % ntn) * BN;

  const int tid = threadIdx.x, wave = tid >> 6, lane = tid & 63;
  const int wm = wave >> 1, wn = wave & 1;
  __shared__ ushort sA[2][8192];
  __shared__ ushort sB[2][BN * 32];
  f32x4 acc[4][NF] = {};

  const int lr = lane >> 2;
  const int ci = lane & 3;
  const int scol = (ci ^ ((lr >> 1) & 3)) * 8;
  const int rA = lane & 15;
  const int cswz = ((lane >> 4) ^ ((rA >> 1) & 3)) * 8;

  const ushort* pA0 = Ag + (size_t)(m0 + (2 * wave) * 16 + lr) * CC + scol;
  const ushort* pA1 = Ag + (size_t)(m0 + (2 * wave + 1) * 16 + lr) * CC + scol;
  const ushort* Bh_ = Bgh + (EPI == 2 ? (size_t)(m0 >> 12) * 262144 : 0);
  const ushort* pB0 = Bh_ + (size_t)(n0 + wave * 16 + lr) * CC + scol;

#define STAGE(T, S)                                                        \
  {                                                                        \
    gload16(pA0 + (T) * 32, &sA[S][(2 * wave) * 512]);                     \
    gload16(pA1 + (T) * 32, &sA[S][(2 * wave + 1) * 512]);                 \
    if (BCH == 8) {                                                        \
      gload16(pB0 + (T) * 32, &sB[S][wave * 512]);                         \
    } else {                                                               \
      if (wave < BCH) gload16(pB0 + (T) * 32, &sB[S][wave * 512]);         \
    }                                                                      \
  }

  STAGE(0, 0);
  __syncthreads();

  #pragma unroll
  for (int t = 0; t < 16; ++t) {
    if (t < 15) STAGE(t + 1, (t + 1) & 1);
    const int cur = t & 1;
    bf16x8 af[4], bhf[NF];
    #pragma unroll
    for (int m = 0; m < 4; ++m)
      af[m] = *(const bf16x8*)(&sA[cur][(wm * 64 + m * 16 + rA) * 32 + cswz]);
    #pragma unroll
    for (int n = 0; n < NF; ++n)
      bhf[n] = *(const bf16x8*)(&sB[cur][(wn * (BN / 2) + n * 16 + rA) * 32 + cswz]);
    #pragma unroll
    for (int m = 0; m < 4; ++m)
      #pragma unroll
      for (int n = 0; n < NF; ++n)
        acc[m][n] = __builtin_amdgcn_mfma_f32_16x16x32_bf16(af[m], bhf[n], acc[m][n], 0, 0, 0);
    __syncthreads();
  }
#undef STAGE

  const int kj = lane >> 4, l15 = lane & 15;
  #pragma unroll
  for (int m = 0; m < 4; ++m) {
    #pragma unroll
    for (int n = 0; n < NF; ++n) {
      if (EPI == 2) {
        #pragma unroll
        for (int r = 0; r < 4; ++r) {
          int row = m0 + wm * 64 + m * 16 + kj * 4 + r;
          int col = n0 + wn * (BN / 2) + n * 16 + l15;
          int nseq = row & (NN - 1), b = row >> 12;
          float val = acc[m][n][r] * gate[nseq] + bias[b * 512 + col];
          outF[(size_t)row * ncols + col] = val;
        }
      } else {
        int rowb = m0 + wm * 64 + m * 16 + kj * 4;
        int col = n0 + wn * (BN / 2) + n * 16 + l15;
        int nseqb = rowb & (NN - 1), b = rowb >> 12;
        int part = col >> 9, h = (col >> 6) & 7, dd = col & 63;
        ushort4 pk;
        #pragma unroll
        for (int r = 0; r < 4; ++r) {
          int nseq = nseqb + r;
          float val = acc[m][n][r] * gate[nseq] + bias[col];
          float e = val > 0.f ? val + 1.f : expf(val);  // elu+1
          ((ushort*)&pk)[r] = f2b(e * ropem[nseq * 64 + dd]);
        }
        ushort* dst = (part == 0 ? qT : kT) +
                      ((size_t)(b * HH + h) * DD + dd) * NN + nseqb;
        *(ushort4*)dst = pk;
      }
    }
  }
}

// ---------------------------------------------------------------------------
// K5a: ctx via MFMA from global; 512 blocks, in-block LDS reduce.
// ---------------------------------------------------------------------------
__global__ __launch_bounds__(256) void k_ctx_mfma(
    const ushort* __restrict__ qT, const ushort* __restrict__ kT,
    float* __restrict__ ctxp) {
  int blk = blockIdx.x;
  int bh = blk >> 4, chunk = blk & 15;
  int wave = threadIdx.x >> 6, lane = threadIdx.x & 63;
  int l15 = lane & 15, kj = lane >> 4;
  const size_t base = (size_t)bh * DD * NN;
  const int n0 = chunk * 256 + wave * 64;
  f32x4 acc[4][4] = {};
  #pragma unroll
  for (int ks = 0; ks < 2; ++ks) {
    const int nb = n0 + ks * 32 + kj * 8;
    bf16x8 qa[4], ka[4];
    #pragma unroll
    for (int m = 0; m < 4; ++m)
      qa[m] = *(const bf16x8*)(qT + base + (size_t)(m * 16 + l15) * NN + nb);
    #pragma unroll
    for (int n = 0; n < 4; ++n)
      ka[n] = *(const bf16x8*)(kT + base + (size_t)(n * 16 + l15) * NN + nb);
    #pragma unroll
    for (int m = 0; m < 4; ++m)
      #pragma unroll
      for (int n = 0; n < 4; ++n)
        acc[m][n] = __builtin_amdgcn_mfma_f32_16x16x32_bf16(qa[m], ka[n], acc[m][n], 0, 0, 0);
  }
  __shared__ float red[4][4096];
  #pragma unroll
  for (int m = 0; m < 4; ++m)
    #pragma unroll
    for (int n = 0; n < 4; ++n)
      #pragma unroll
      for (int r = 0; r < 4; ++r)
        red[wave][(m * 16 + kj * 4 + r) * 64 + n * 16 + l15] = acc[m][n][r];
  __syncthreads();
  const float scale = 1.f / 512.f;
  float* dst = ctxp + (size_t)(bh * 16 + chunk) * 4096;
  #pragma unroll
  for (int e = 0; e < 16; ++e) {
    int idx = threadIdx.x + e * 256;
    float s = red[0][idx] + red[1][idx] + red[2][idx] + red[3][idx];
    dst[idx] = s * scale;
  }
}

// K5b: reduce 16 partials -> ctx[bh][64][64]
__global__ void k_ctx_red(const float* __restrict__ ctxp, float* __restrict__ ctx) {
  int idx = blockIdx.x * 256 + threadIdx.x;
  int bh = idx >> 12, off = idx & 4095;
  float s = 0.f;
  #pragma unroll
  for (int c2 = 0; c2 < 16; ++c2)
    s += ctxp[((size_t)bh * 16 + c2) * 4096 + off];
  ctx[idx] = s;
}

// ---------------------------------------------------------------------------
// K6: Mf[b][o][h*64+d] = (1/512)*sum_e ctx[b,h,d,e]*wp[o,h*64+e]; bf16 hi/lo.
// ---------------------------------------------------------------------------
__global__ __launch_bounds__(256) void k_mproj(
    const float* __restrict__ ctx, const float* __restrict__ wp,
    ushort* __restrict__ Mfh, ushort* __restrict__ Mfl) {
  int blk = blockIdx.x;
  int b = blk >> 6, h = (blk >> 3) & 7, oq = blk & 7;
  int tid = threadIdx.x;
  int o = oq * 64 + (tid & 63);
  int d0 = (tid >> 6) * 16;
  __shared__ float cs[64][64];
  #pragma unroll
  for (int it = 0; it < 4; ++it) {
    int idx = (tid + 256 * it) * 4;
    *(float4*)&cs[idx >> 6][idx & 63] =
        *(const float4*)&ctx[(size_t)(b * 8 + h) * 4096 + idx];
  }
  __syncthreads();
  float wv[64];
  #pragma unroll
  for (int e = 0; e < 64; ++e) wv[e] = wp[(size_t)o * 512 + h * 64 + e];
  for (int d = d0; d < d0 + 16; ++d) {
    float s = 0.f;
    #pragma unroll
    for (int e = 0; e < 64; ++e) s += cs[d][e] * wv[e];
    s *= (1.f / 512.f);
    ushort hi = f2b(s);
    size_t idx = ((size_t)b * 512 + o) * 512 + h * 64 + d;
    Mfh[idx] = hi;
    Mfl[idx] = f2b(s - b2f(hi));
  }
}

// ---------------------------------------------------------------------------
// K_TAIL: blk 0..63 g2 (4-wave 128-tile MFMA GEMM, 2-term B, bf16 out);
//         blk 64..575 beff.
// ---------------------------------------------------------------------------
__global__ __launch_bounds__(256) void k_tail(
    const ushort* __restrict__ Mfh, const ushort* __restrict__ Mfl,
    const ushort* __restrict__ Wvth, const ushort* __restrict__ Wvtl,
    ushort* __restrict__ G2h,
    const float* __restrict__ bqkv, const float* __restrict__ bproj,
    float* __restrict__ beff) {
  const int blk = blockIdx.x;
  if (blk < 64) {
    const int logical = (blk & 7) * 8 + (blk >> 3);
    const int m0 = (logical / 4) * 128, n0 = (logical % 4) * 128;
    const int tid = threadIdx.x, wave = tid >> 6, lane = tid & 63;
    const int wm = wave >> 1, wn = wave & 1;
    __shared__ ushort sA[2][4096];
    __shared__ ushort sB[2][8192];
    f32x4 acc[4][4] = {};

    const int lr = lane >> 2;
    const int ci = lane & 3;
    const int scol = (ci ^ ((lr >> 1) & 3)) * 8;
    const int rA = lane & 15;
    const int cswz = ((lane >> 4) ^ ((rA >> 1) & 3)) * 8;

    const int chunk0 = wave * 2, chunk1 = wave * 2 + 1;
    const ushort* pA0 = Mfh + (size_t)(m0 + chunk0 * 16 + lr) * CC + scol;
    const ushort* pA1 = Mfh + (size_t)(m0 + chunk1 * 16 + lr) * CC + scol;
    const ushort* pB0 = Wvth + (size_t)(n0 + chunk0 * 16 + lr) * CC + scol;
    const ushort* pB1 = Wvth + (size_t)(n0 + chunk1 * 16 + lr) * CC + scol;
    const ushort* pB0l = Wvtl + (size_t)(n0 + chunk0 * 16 + lr) * CC + scol;
    const ushort* pB1l = Wvtl + (size_t)(n0 + chunk1 * 16 + lr) * CC + scol;

#define STAGE(T, S)                                                        \
    {                                                                      \
      gload16(pA0 + (T) * 32, &sA[S][chunk0 * 512]);                       \
      gload16(pA1 + (T) * 32, &sA[S][chunk1 * 512]);                       \
      gload16(pB0 + (T) * 32, &sB[S][chunk0 * 512]);                       \
      gload16(pB1 + (T) * 32, &sB[S][chunk1 * 512]);                       \
      gload16(pB0l + (T) * 32, &sB[S][4096 + chunk0 * 512]);               \
      gload16(pB1l + (T) * 32, &sB[S][4096 + chunk1 * 512]);               \
    }

    STAGE(0, 0);
    __syncthreads();
    #pragma unroll
    for (int t = 0; t < 16; ++t) {
      if (t < 15) STAGE(t + 1, (t + 1) & 1);
      const int cur = t & 1;
      bf16x8 af[4], bh[4], bl[4];
      #pragma unroll
      for (int m = 0; m < 4; ++m)
        af[m] = *(const bf16x8*)(&sA[cur][(wm * 64 + m * 16 + rA) * 32 + cswz]);
      #pragma unroll
      for (int n = 0; n < 4; ++n) {
        int off = (wn * 64 + n * 16 + rA) * 32 + cswz;
        bh[n] = *(const bf16x8*)(&sB[cur][off]);
        bl[n] = *(const bf16x8*)(&sB[cur][4096 + off]);
      }
      #pragma unroll
      for (int m = 0; m < 4; ++m)
        #pragma unroll
        for (int n = 0; n < 4; ++n) {
          acc[m][n] = __builtin_amdgcn_mfma_f32_16x16x32_bf16(af[m], bh[n], acc[m][n], 0, 0, 0);
          acc[m][n] = __builtin_amdgcn_mfma_f32_16x16x32_bf16(af[m], bl[n], acc[m][n], 0, 0, 0);
        }
      __syncthreads();
    }
#undef STAGE

    const int kj = lane >> 4, l15 = lane & 15;
    #pragma unroll
    for (int m = 0; m < 4; ++m)
      #pragma unroll
      for (int n = 0; n < 4; ++n)
        #pragma unroll
        for (int r = 0; r < 4; ++r) {
          int row = m0 + wm * 64 + m * 16 + kj * 4 + r;
          int col = n0 + wn * 64 + n * 16 + l15;
          G2h[(size_t)row * 512 + col] = f2b(acc[m][n][r]);
        }
  } else {
    int w = threadIdx.x >> 6, lane = threadIdx.x & 63;
    int t = (blk - 64) * 4 + w;
    int b = t >> 9, o = t & 511;
    size_t base = ((size_t)b * 512 + o) * 512;
    float s = 0.f;
    #pragma unroll
    for (int c = 0; c < 512; c += 64) {
      float m = b2f(Mfh[base + c + lane]) + b2f(Mfl[base + c + lane]);
      s += bqkv[1024 + c + lane] * m;
    }
    #pragma unroll
    for (int off = 32; off > 0; off >>= 1) s += __shfl_down(s, off);
    if (lane == 0) beff[t] = s + bproj[o];
  }
}

// ---------------------------------------------------------------------------
extern "C" void kernel_launch(void* const* d_in, const int* in_sizes, int n_in,
                              void* d_out, int out_size, void* d_ws, size_t ws_size,
                              hipStream_t stream) {
  const float* x    = (const float*)d_in[0];
  const float* lpw  = (const float*)d_in[1];
  const float* lvw  = (const float*)d_in[2];
  const float* wqkv = (const float*)d_in[3];
  const float* bqkv = (const float*)d_in[4];
  const float* wproj= (const float*)d_in[5];
  const float* bproj= (const float*)d_in[6];
  const float* omega= (const float*)d_in[7];
  const float* w1   = (const float*)d_in[8];
  const float* b1   = (const float*)d_in[9];
  const float* w2   = (const float*)d_in[10];
  const float* b2   = (const float*)d_in[11];
  const float* wg   = (const float*)d_in[12];
  const float* bg   = (const float*)d_in[13];
  float* out = (float*)d_out;

  constexpr size_t MB = 1024 * 1024;
  char* w = (char*)d_ws;
  int*   pcntP  = (int*)(w);                      // 64 KiB
  int*   pcntV  = (int*)(w + 64 * 1024);          // 64 KiB
  float* attn   = (float*)(w + 128 * 1024);
  float* gate   = (float*)(w + 144 * 1024);
  float* etabP  = (float*)(w + 160 * 1024);
  float* etabV  = (float*)(w + 176 * 1024);
  float* fcntP  = (float*)(w + 192 * 1024);
  float* fcntV  = (float*)(w + 208 * 1024);
  float* pe2    = (float*)(w + 256 * 1024);       // 1 MiB
  float* gpe    = (float*)(w + 1280 * 1024);
  float* ropem  = (float*)(w + 1344 * 1024);      // 1 MiB
  ushort* Xh    = (ushort*)(w + 4 * MB);          // 16 MiB
  ushort* qT    = (ushort*)(w + 20 * MB);         // 16 MiB [B,H,D,N]
  ushort* kT    = (ushort*)(w + 36 * MB);         // 16 MiB
  ushort* Whqk  = (ushort*)(w + 52 * MB);         // 1 MiB
  ushort* Wvth  = (ushort*)(w + 53 * MB);         // 0.5 MiB
  ushort* Wvtl  = (ushort*)(w + 53 * MB + 512 * 1024);  // 0.5 MiB
  ushort* Mfh   = (ushort*)(w + 54 * MB);         // 2 MiB [B*512][512]
  ushort* Mfl   = (ushort*)(w + 56 * MB);         // 2 MiB
  ushort* G2h   = (ushort*)(w + 58 * MB);         // 2 MiB
  float* beff   = (float*)(w + 60 * MB);          // 8 KiB
  float* ctxp   = (float*)(w + 61 * MB);          // 8 MiB
  float* ctx    = (float*)(w + 69 * MB);          // 0.5 MiB -> 69.5 MiB

  // fused front: counts_prep (1024) | pe (512) | prep_h (256) | prep_wvt (64)
  k_front<<<1856, 512, 0, stream>>>(x, pcntP, pcntV, Xh, omega, w1, b1, w2, b2,
                                    pe2, wqkv, Whqk, Wvth, Wvtl);
  // fused: etab2 (16) | gatepe (1)
  k_mid1<<<17, 256, 0, stream>>>(lpw, lvw, pcntP, pcntV, etabP, etabV,
                                 fcntP, fcntV, pe2, wg, bg, gpe);
  // fused: gsum (4096) | ropemul (1024)
  k_mid2<<<5120, 256, 0, stream>>>(fcntP, fcntV, etabP, etabV, attn,
                                   pe2, gpe, ropem);
  k_norm<<<1, 1024, 0, stream>>>(attn, gate);

  // q,k GEMM: M=16384, N=1024 -> 512 blocks (2/CU), 512 threads
  k_gemm8<128, 1><<<512, 512, 0, stream>>>(Xh, Whqk, bqkv, gate, ropem,
                                           nullptr, qT, kT, 8, 0);
  k_ctx_mfma<<<512, 256, 0, stream>>>(qT, kT, ctxp);
  k_ctx_red<<<512, 256, 0, stream>>>(ctxp, ctx);
  k_mproj<<<256, 256, 0, stream>>>(ctx, wproj, Mfh, Mfl);
  // fused: g2 (64) | beff (512)
  k_tail<<<576, 256, 0, stream>>>(Mfh, Mfl, Wvth, Wvtl, G2h, bqkv, bproj, beff);

  // out GEMM: M=16384, N=512, BN=64 -> 512 blocks, 512 threads
  k_gemm8<64, 2><<<512, 512, 0, stream>>>(Xh, G2h, beff, gate, nullptr,
                                          out, nullptr, nullptr, 8, 512);
}